// Round 5
// baseline (1929.100 us; speedup 1.0000x reference)
//
#include <hip/hip_runtime.h>
#include <stdint.h>

#define GAS __attribute__((address_space(1)))
#define LAS __attribute__((address_space(3)))

typedef __bf16 bf16x8 __attribute__((ext_vector_type(8)));
typedef _Float16 f16x8 __attribute__((ext_vector_type(8)));
typedef float f32x4 __attribute__((ext_vector_type(4)));
typedef unsigned u32x4 __attribute__((ext_vector_type(4)));

__device__ __forceinline__ unsigned short f2bf(float f) {
  unsigned u = __float_as_uint(f);
  unsigned r = (u + 0x7FFFu + ((u >> 16) & 1u)) >> 16;
  return (unsigned short)r;
}

__device__ __forceinline__ float sigmoidf(float x) {
  return 1.f / (1.f + expf(-x));
}

__device__ __forceinline__ unsigned f16bits(float x) {
  _Float16 h = (_Float16)x;
  return (unsigned)__builtin_bit_cast(unsigned short, h);
}

// MALL-coherent tagged-word store (single dword, no tearing).
__device__ __forceinline__ void st1c(unsigned* p, unsigned v) {
  __hip_atomic_store(p, v, __ATOMIC_RELAXED, __HIP_MEMORY_SCOPE_AGENT);
}

// MALL-coherent 16B load with compile-time byte offset.
// Result is IN FLIGHT until s_waitcnt vmcnt(0)!
template <int OFF>
__device__ __forceinline__ u32x4 ld4c(const unsigned* p) {
  u32x4 r;
  asm volatile("global_load_dwordx4 %0, %1, off offset:%2 sc0 sc1"
               : "=v"(r) : "v"(p), "n"(OFF) : "memory");
  return r;
}

// ---------------- gather: x_bf16 [4096,512] from seq; word_emb f32 [64,512] ----
__global__ __launch_bounds__(128) void k_gather(
    const float* __restrict__ emb, const int* __restrict__ seq,
    const int* __restrict__ word, unsigned short* __restrict__ xbf,
    float* __restrict__ wemb) {
  int row = blockIdx.x;
  int tid = threadIdx.x;
  if (row < 4096) {
    const float* src = emb + (size_t)seq[row] * 512;
    unsigned short* dst = xbf + (size_t)row * 512;
    for (int e = tid; e < 512; e += 128) dst[e] = f2bf(src[e]);
  } else {
    int b = row - 4096;
    const float* src = emb + (size_t)word[b] * 512;
    float* dst = wemb + (size_t)b * 512;
    for (int e = tid; e < 512; e += 128) dst[e] = src[e];
  }
}

// ---------------- weight conversion: wih_bf [1536,512], dec_bf [32000,512] ----
__global__ __launch_bounds__(128) void k_conv(
    const float* __restrict__ Wih, const float* __restrict__ decW,
    unsigned short* __restrict__ wih_bf, unsigned short* __restrict__ dec_bf) {
  int row = blockIdx.x;
  int tid = threadIdx.x;
  if (row < 1536) {
    const float* s = Wih + (size_t)row * 512;
    unsigned short* d = wih_bf + (size_t)row * 512;
    for (int e = tid; e < 512; e += 128) d[e] = f2bf(s[e]);
  } else {
    int o = row - 1536;
    const float* s = decW + (size_t)o * 512;
    unsigned short* d = dec_bf + (size_t)o * 512;
    for (int e = tid; e < 512; e += 128) d[e] = f2bf(s[e]);
  }
}

// ---------------- step-invariant gate preactivations from word_emb ------------
__global__ __launch_bounds__(256) void k_pre(
    const float* __restrict__ ztW, const float* __restrict__ ztb,
    const float* __restrict__ rtW, const float* __restrict__ rtb,
    const float* __restrict__ wemb, float* __restrict__ ztp,
    float* __restrict__ rtp) {
  int idx = blockIdx.x * 256 + threadIdx.x;
  int b = idx >> 10, o = idx & 1023;
  const float4* we = (const float4*)(wemb + (size_t)b * 512);
  const float4* wr;
  float acc;
  if (o < 512) { wr = (const float4*)(ztW + (size_t)o * 1024); acc = ztb[o]; }
  else { wr = (const float4*)(rtW + (size_t)(o - 512) * 1024); acc = rtb[o - 512]; }
  for (int c = 0; c < 128; ++c) {
    float4 w = wr[c], e = we[c];
    acc += w.x * e.x + w.y * e.y + w.z * e.z + w.w * e.w;
  }
  if (o < 512) ztp[(size_t)b * 512 + o] = acc;
  else rtp[(size_t)b * 512 + (o - 512)] = acc;
}

// ---------------- bf16 GEMM, C[m,n] = sum_k A[m,k]*B[n,k] + bias[n] ----------
__global__ __launch_bounds__(256) void k_gemm_bt(
    const unsigned short* __restrict__ A, const unsigned short* __restrict__ B,
    float* __restrict__ C, const float* __restrict__ bias,
    int M, int N, int K) {
  __shared__ __align__(16) unsigned short As[128 * 32];
  __shared__ __align__(16) unsigned short Bs[128 * 32];
  int nt = N >> 7;
  int nwg = gridDim.x;
  int bid = blockIdx.x;
  int swz = (bid & 7) * (nwg >> 3) + (bid >> 3);  // XCD swizzle (nwg % 8 == 0)
  int m0 = (swz / nt) << 7, n0 = (swz % nt) << 7;
  int tid = threadIdx.x;
  int l = tid & 63, w = tid >> 6;
  int wr = w >> 1, wc = w & 1;
  int lr = l & 15, lk = l >> 4;
  f32x4 acc[4][4] = {};
  for (int k0 = 0; k0 < K; k0 += 32) {
#pragma unroll
    for (int i = 0; i < 2; ++i) {
      int c = w * 2 + i;
      int off = c * 1024 + l * 16;
      int row = off >> 6, kb = off & 63;
      const char* ga = (const char*)A + ((size_t)(m0 + row) * K + k0) * 2 + kb;
      const char* gb = (const char*)B + ((size_t)(n0 + row) * K + k0) * 2 + kb;
      __builtin_amdgcn_global_load_lds((const GAS void*)ga,
                                       (LAS void*)((char*)As + c * 1024), 16, 0, 0);
      __builtin_amdgcn_global_load_lds((const GAS void*)gb,
                                       (LAS void*)((char*)Bs + c * 1024), 16, 0, 0);
    }
    asm volatile("s_waitcnt vmcnt(0)" ::: "memory");
    __syncthreads();
    bf16x8 af[4], bfr[4];
#pragma unroll
    for (int i = 0; i < 4; ++i)
      af[i] = *(const bf16x8*)&As[(wr * 64 + i * 16 + lr) * 32 + lk * 8];
#pragma unroll
    for (int i = 0; i < 4; ++i)
      bfr[i] = *(const bf16x8*)&Bs[(wc * 64 + i * 16 + lr) * 32 + lk * 8];
#pragma unroll
    for (int i = 0; i < 4; ++i)
#pragma unroll
      for (int jj = 0; jj < 4; ++jj)
        acc[i][jj] = __builtin_amdgcn_mfma_f32_16x16x32_bf16(af[i], bfr[jj], acc[i][jj], 0, 0, 0);
    __syncthreads();
  }
#pragma unroll
  for (int jj = 0; jj < 4; ++jj) {
    int col = n0 + wc * 64 + jj * 16 + lr;
    float bv = bias ? bias[col] : 0.f;
#pragma unroll
    for (int i = 0; i < 4; ++i) {
      int rb = m0 + wr * 64 + i * 16 + lk * 4;
#pragma unroll
      for (int q = 0; q < 4; ++q)
        C[(size_t)(rb + q) * N + col] = acc[i][jj][q] + bv;
    }
  }
}

// ---------------- recurrence: tagged dataflow, no barriers --------------------
// 32 wgs; wg g owns state cols [16g,16g+16); weights f16 in LDS. Exchange
// arrays are u32 cells = (phase_tag<<16)|f16. Consumers poll the data itself:
// re-load fragments until all tags match, then data is already in registers.
// Waves are fully independent (4 batch-row bands x 32 wgs pipelines).
struct RnnP {
  const float *Whh, *ztW, *rtW, *htW;
  const float *gi, *ztp, *rtp, *wemb, *inith, *bhh, *htb;
  unsigned *hcurT, *hgruT, *rwT;
  unsigned short *outsb;
  float *hfin;
};

// acc[n] += A(band w) x WL-slice, where A arrives as tagged u32 [64][512].
template <int NT>
__device__ __forceinline__ void mm_poll(f32x4* acc, const unsigned* At,
                                        const _Float16* WLrow, unsigned tag,
                                        int w, int lr, int lk) {
  u32x4 raw[32];
  const unsigned* arow = At + ((size_t)(16 * w + lr)) * 512 + lk * 8;
  const unsigned texp = tag << 16;
  for (;;) {
#define LD2(c) \
    raw[2 * (c)] = ld4c<(c) * 128>(arow); \
    raw[2 * (c) + 1] = ld4c<(c) * 128 + 16>(arow);
    LD2(0) LD2(1) LD2(2) LD2(3) LD2(4) LD2(5) LD2(6) LD2(7)
    LD2(8) LD2(9) LD2(10) LD2(11) LD2(12) LD2(13) LD2(14) LD2(15)
#undef LD2
    asm volatile("s_waitcnt vmcnt(0)" ::: "memory");
    __builtin_amdgcn_sched_barrier(0);
    unsigned bad = 0;
#pragma unroll
    for (int i = 0; i < 32; ++i) {
      u32x4 v = raw[i];
      bad |= (v.x ^ texp) | (v.y ^ texp) | (v.z ^ texp) | (v.w ^ texp);
    }
    if (__all((int)((bad >> 16) == 0u))) break;
  }
  __builtin_amdgcn_sched_barrier(0);
#pragma unroll
  for (int c = 0; c < 16; ++c) {
    unsigned p0 = __builtin_amdgcn_perm(raw[2 * c].y, raw[2 * c].x, 0x05040100);
    unsigned p1 = __builtin_amdgcn_perm(raw[2 * c].w, raw[2 * c].z, 0x05040100);
    unsigned p2 = __builtin_amdgcn_perm(raw[2 * c + 1].y, raw[2 * c + 1].x, 0x05040100);
    unsigned p3 = __builtin_amdgcn_perm(raw[2 * c + 1].w, raw[2 * c + 1].z, 0x05040100);
    u32x4 pk = {p0, p1, p2, p3};
    f16x8 a = __builtin_bit_cast(f16x8, pk);
#pragma unroll
    for (int n = 0; n < NT; ++n) {
      f16x8 bb = *(const f16x8*)(WLrow + (n * 16 + lr) * 520 + c * 32 + lk * 8);
      acc[n] = __builtin_amdgcn_mfma_f32_16x16x32_f16(a, bb, acc[n], 0, 0, 0);
    }
  }
}

__global__ __launch_bounds__(256, 1) void k_rnn3(RnnP p) {
  const int g = blockIdx.x, tid = threadIdx.x;
  const int w = tid >> 6, l = tid & 63;
  const int lr = l & 15, lk = l >> 4;
  // 112 rows x 520 halfs (512 + 8 pad)
  __shared__ _Float16 WL[112 * 520];
  for (int idx = tid; idx < 112 * 512; idx += 256) {
    int rr = idx >> 9, e = idx & 511;
    const float* src;
    if (rr < 48) {
      int gate = rr >> 4, i = rr & 15;
      src = p.Whh + ((size_t)(gate * 512 + g * 16 + i)) * 512 + e;
    } else if (rr < 96) {
      int r2 = rr - 48, gate = r2 >> 4, i = r2 & 15;
      const float* base = gate == 0 ? p.ztW : (gate == 1 ? p.rtW : p.htW);
      src = base + ((size_t)(g * 16 + i)) * 1024 + 512 + e;
    } else {
      int i = rr - 96;
      src = p.htW + ((size_t)(g * 16 + i)) * 1024 + e;
    }
    WL[rr * 520 + e] = (_Float16)(*src);
  }
  __syncthreads();  // WL read-only afterwards; no further block syncs
  // ---- per-lane owned coordinates: col j, batch rows brow..brow+3 ----
  const int j = g * 16 + lr;
  const int brow = 16 * w + lk * 4;
  f32x4 hprev, zp, rp, wev;
#pragma unroll
  for (int q = 0; q < 4; ++q) {
    int b = brow + q;
    hprev[q] = p.inith[(size_t)b * 512 + j];
    zp[q] = p.ztp[(size_t)b * 512 + j];
    rp[q] = p.rtp[(size_t)b * 512 + j];
    wev[q] = p.wemb[(size_t)b * 512 + j];
  }
  const float br = p.bhh[j], bz = p.bhh[512 + j], bn = p.bhh[1024 + j];
  const float bht = p.htb[j];
  float gir[12];
#pragma unroll
  for (int q = 0; q < 4; ++q) {
    const float* git = p.gi + (size_t)(brow + q) * 1536;
    gir[q * 3 + 0] = git[j];
    gir[q * 3 + 1] = git[512 + j];
    gir[q * 3 + 2] = git[1024 + j];
  }
  // publish initial h (tag 3)
#pragma unroll
  for (int q = 0; q < 4; ++q)
    st1c(&p.hcurT[(size_t)(brow + q) * 512 + j], (3u << 16) | f16bits(hprev[q]));
  for (int t = 0; t < 64; ++t) {
    const unsigned tg = 3u * (unsigned)t;
    // ---- phase 1: gates r,z,n ; h_gru ----
    f32x4 acc1[3] = {};
    mm_poll<3>(acc1, p.hcurT, &WL[0], tg + 3, w, lr, lk);
    f32x4 hg;
#pragma unroll
    for (int q = 0; q < 4; ++q) {
      int b = brow + q;
      float r = sigmoidf(gir[q * 3 + 0] + br + acc1[0][q]);
      float z = sigmoidf(gir[q * 3 + 1] + bz + acc1[1][q]);
      float n = tanhf(gir[q * 3 + 2] + r * (acc1[2][q] + bn));
      float hgq = (1.f - z) * n + z * hprev[q];
      hg[q] = hgq;
      st1c(&p.hgruT[(size_t)b * 512 + j], ((tg + 4) << 16) | f16bits(hgq));
      p.outsb[((size_t)t * 64 + b) * 512 + j] = f2bf(hgq);
    }
    // ---- phase 2: zt, rt, htB ----
    f32x4 acc2[3] = {};
    mm_poll<3>(acc2, p.hgruT, &WL[48 * 520], tg + 4, w, lr, lk);
    f32x4 zt, htB;
#pragma unroll
    for (int q = 0; q < 4; ++q) {
      int b = brow + q;
      float ztq = sigmoidf(zp[q] + acc2[0][q]);
      float rtq = sigmoidf(rp[q] + acc2[1][q]);
      zt[q] = ztq;
      htB[q] = acc2[2][q];
      st1c(&p.rwT[(size_t)b * 512 + j], ((tg + 5) << 16) | f16bits(rtq * wev[q]));
    }
    // prefetch next step's gi (plain cached loads; hides under phase 3)
    if (t < 63) {
      const float* git = p.gi + (size_t)(t + 1) * 64 * 1536;
#pragma unroll
      for (int q = 0; q < 4; ++q) {
        const float* gb = git + (size_t)(brow + q) * 1536;
        gir[q * 3 + 0] = gb[j];
        gir[q * 3 + 1] = gb[512 + j];
        gir[q * 3 + 2] = gb[1024 + j];
      }
    }
    // ---- phase 3: htA ; h_new ----
    f32x4 acc3[1] = {};
    mm_poll<1>(acc3, p.rwT, &WL[96 * 520], tg + 5, w, lr, lk);
#pragma unroll
    for (int q = 0; q < 4; ++q) {
      int b = brow + q;
      float htl = tanhf(acc3[0][q] + htB[q] + bht);
      float hn2 = (1.f - zt[q]) * hg[q] + zt[q] * htl;
      hprev[q] = hn2;
      if (t < 63) st1c(&p.hcurT[(size_t)b * 512 + j], ((tg + 6) << 16) | f16bits(hn2));
      else p.hfin[(size_t)b * 512 + j] = hn2;
    }
  }
}

extern "C" void kernel_launch(void* const* d_in, const int* in_sizes, int n_in,
                              void* d_out, int out_size, void* d_ws, size_t ws_size,
                              hipStream_t stream) {
  const float* emb   = (const float*)d_in[0];
  const float* Wih   = (const float*)d_in[1];
  const float* Whh   = (const float*)d_in[2];
  const float* bih   = (const float*)d_in[3];
  const float* bhh   = (const float*)d_in[4];
  const float* ztW   = (const float*)d_in[5];
  const float* ztb   = (const float*)d_in[6];
  const float* rtW   = (const float*)d_in[7];
  const float* rtb   = (const float*)d_in[8];
  const float* htW   = (const float*)d_in[9];
  const float* htb   = (const float*)d_in[10];
  const float* decW  = (const float*)d_in[11];
  const float* decb  = (const float*)d_in[12];
  const float* inith = (const float*)d_in[13];
  const int* word    = (const int*)d_in[14];
  const int* seq     = (const int*)d_in[15];
  float* out = (float*)d_out;

  char* ws = (char*)d_ws;
  size_t off = 0;
  auto alloc = [&](size_t bytes) {
    size_t o = off;
    off += (bytes + 255) & ~(size_t)255;
    return o;
  };
  unsigned short* xbf   = (unsigned short*)(ws + alloc(4096ull * 512 * 2));
  unsigned short* wihbf = (unsigned short*)(ws + alloc(1536ull * 512 * 2));
  unsigned short* decbf = (unsigned short*)(ws + alloc(32000ull * 512 * 2));
  float* wemb           = (float*)(ws + alloc(64ull * 512 * 4));
  float* ztp            = (float*)(ws + alloc(64ull * 512 * 4));
  float* rtp            = (float*)(ws + alloc(64ull * 512 * 4));
  float* gi             = (float*)(ws + alloc(4096ull * 1536 * 4));
  unsigned short* outsb = (unsigned short*)(ws + alloc(4096ull * 512 * 2));
  unsigned* hcurT       = (unsigned*)(ws + alloc(64ull * 512 * 4));
  unsigned* hgruT       = (unsigned*)(ws + alloc(64ull * 512 * 4));
  unsigned* rwT         = (unsigned*)(ws + alloc(64ull * 512 * 4));

  hipLaunchKernelGGL(k_gather, dim3(4160), dim3(128), 0, stream,
                     emb, seq, word, xbf, wemb);
  hipLaunchKernelGGL(k_conv, dim3(33536), dim3(128), 0, stream,
                     Wih, decW, wihbf, decbf);
  hipLaunchKernelGGL(k_pre, dim3(256), dim3(256), 0, stream,
                     ztW, ztb, rtW, rtb, wemb, ztp, rtp);
  hipLaunchKernelGGL(k_gemm_bt, dim3(384), dim3(256), 0, stream,
                     xbf, wihbf, gi, bih, 4096, 1536, 512);
  // reset exchange tags (hcurT/hgruT/rwT are contiguous) — replay-safe
  hipMemsetAsync(hcurT, 0, 3ull * 64 * 512 * 4, stream);
  RnnP p{Whh, ztW, rtW, htW, gi, ztp, rtp, wemb, inith, bhh, htb,
         hcurT, hgruT, rwT, outsb, out + 4096ull * 32000};
  hipLaunchKernelGGL(k_rnn3, dim3(32), dim3(256), 0, stream, p);
  hipLaunchKernelGGL(k_gemm_bt, dim3(8000), dim3(256), 0, stream,
                     outsb, decbf, out, decb, 4096, 32000, 512);
}

// Round 7
// 1428.815 us; speedup vs baseline: 1.3501x; 1.3501x over previous
//
#include <hip/hip_runtime.h>
#include <stdint.h>

#define GAS __attribute__((address_space(1)))
#define LAS __attribute__((address_space(3)))

typedef __bf16 bf16x8 __attribute__((ext_vector_type(8)));
typedef _Float16 f16x8 __attribute__((ext_vector_type(8)));
typedef float f32x4 __attribute__((ext_vector_type(4)));
typedef unsigned u32x4 __attribute__((ext_vector_type(4)));

__device__ __forceinline__ unsigned short f2bf(float f) {
  unsigned u = __float_as_uint(f);
  unsigned r = (u + 0x7FFFu + ((u >> 16) & 1u)) >> 16;
  return (unsigned short)r;
}

__device__ __forceinline__ float sigmoidf(float x) {
  return 1.f / (1.f + expf(-x));
}

// ---- MALL-coherent (agent) exchange primitives (verified working r3/r4) -----
__device__ __forceinline__ void st2c(_Float16* p, _Float16 v) {
  unsigned short u = __builtin_bit_cast(unsigned short, v);
  __hip_atomic_store((unsigned short*)p, u, __ATOMIC_RELAXED, __HIP_MEMORY_SCOPE_AGENT);
}
__device__ __forceinline__ void stu2c(unsigned short* p, unsigned short v) {
  __hip_atomic_store(p, v, __ATOMIC_RELAXED, __HIP_MEMORY_SCOPE_AGENT);
}
__device__ __forceinline__ void stf_mall(unsigned* p, unsigned v) {
  __hip_atomic_store(p, v, __ATOMIC_RELAXED, __HIP_MEMORY_SCOPE_AGENT);
}
__device__ __forceinline__ unsigned ldf_mall(const unsigned* p) {
  return __hip_atomic_load(p, __ATOMIC_RELAXED, __HIP_MEMORY_SCOPE_AGENT);
}
// 16B MALL-coherent load; result IN FLIGHT until s_waitcnt vmcnt(0)!
__device__ __forceinline__ u32x4 ld16_mall(const void* p) {
  u32x4 r;
  asm volatile("global_load_dwordx4 %0, %1, off sc0 sc1"
               : "=v"(r) : "v"(p) : "memory");
  return r;
}
template <int OFF>
__device__ __forceinline__ f16x8 ldh8_mall(const _Float16* p) {
  u32x4 r;
  asm volatile("global_load_dwordx4 %0, %1, off offset:%2 sc0 sc1"
               : "=v"(r) : "v"(p), "n"(OFF) : "memory");
  return __builtin_bit_cast(f16x8, r);
}

// ---------------- gather: x_bf16 [4096,512] from seq; word_emb f32 [64,512] ----
__global__ __launch_bounds__(128) void k_gather(
    const float* __restrict__ emb, const int* __restrict__ seq,
    const int* __restrict__ word, unsigned short* __restrict__ xbf,
    float* __restrict__ wemb) {
  int row = blockIdx.x;
  int tid = threadIdx.x;
  if (row < 4096) {
    const float* src = emb + (size_t)seq[row] * 512;
    unsigned short* dst = xbf + (size_t)row * 512;
    for (int e = tid; e < 512; e += 128) dst[e] = f2bf(src[e]);
  } else {
    int b = row - 4096;
    const float* src = emb + (size_t)word[b] * 512;
    float* dst = wemb + (size_t)b * 512;
    for (int e = tid; e < 512; e += 128) dst[e] = src[e];
  }
}

// ---------------- weight conversion: wih_bf [1536,512], dec_bf [32000,512] ----
__global__ __launch_bounds__(128) void k_conv(
    const float* __restrict__ Wih, const float* __restrict__ decW,
    unsigned short* __restrict__ wih_bf, unsigned short* __restrict__ dec_bf) {
  int row = blockIdx.x;
  int tid = threadIdx.x;
  if (row < 1536) {
    const float* s = Wih + (size_t)row * 512;
    unsigned short* d = wih_bf + (size_t)row * 512;
    for (int e = tid; e < 512; e += 128) d[e] = f2bf(s[e]);
  } else {
    int o = row - 1536;
    const float* s = decW + (size_t)o * 512;
    unsigned short* d = dec_bf + (size_t)o * 512;
    for (int e = tid; e < 512; e += 128) d[e] = f2bf(s[e]);
  }
}

// ---------------- step-invariant gate preactivations from word_emb ------------
__global__ __launch_bounds__(256) void k_pre(
    const float* __restrict__ ztW, const float* __restrict__ ztb,
    const float* __restrict__ rtW, const float* __restrict__ rtb,
    const float* __restrict__ wemb, float* __restrict__ ztp,
    float* __restrict__ rtp) {
  int idx = blockIdx.x * 256 + threadIdx.x;
  int b = idx >> 10, o = idx & 1023;
  const float4* we = (const float4*)(wemb + (size_t)b * 512);
  const float4* wr;
  float acc;
  if (o < 512) { wr = (const float4*)(ztW + (size_t)o * 1024); acc = ztb[o]; }
  else { wr = (const float4*)(rtW + (size_t)(o - 512) * 1024); acc = rtb[o - 512]; }
  for (int c = 0; c < 128; ++c) {
    float4 w = wr[c], e = we[c];
    acc += w.x * e.x + w.y * e.y + w.z * e.z + w.w * e.w;
  }
  if (o < 512) ztp[(size_t)b * 512 + o] = acc;
  else rtp[(size_t)b * 512 + (o - 512)] = acc;
}

// ---------------- bf16 GEMM (used for gi only now) ---------------------------
__global__ __launch_bounds__(256) void k_gemm_bt(
    const unsigned short* __restrict__ A, const unsigned short* __restrict__ B,
    float* __restrict__ C, const float* __restrict__ bias,
    int M, int N, int K) {
  __shared__ __align__(16) unsigned short As[128 * 32];
  __shared__ __align__(16) unsigned short Bs[128 * 32];
  int nt = N >> 7;
  int nwg = gridDim.x;
  int bid = blockIdx.x;
  int swz = (bid & 7) * (nwg >> 3) + (bid >> 3);
  int m0 = (swz / nt) << 7, n0 = (swz % nt) << 7;
  int tid = threadIdx.x;
  int l = tid & 63, w = tid >> 6;
  int wr = w >> 1, wc = w & 1;
  int lr = l & 15, lk = l >> 4;
  f32x4 acc[4][4] = {};
  for (int k0 = 0; k0 < K; k0 += 32) {
#pragma unroll
    for (int i = 0; i < 2; ++i) {
      int c = w * 2 + i;
      int off = c * 1024 + l * 16;
      int row = off >> 6, kb = off & 63;
      const char* ga = (const char*)A + ((size_t)(m0 + row) * K + k0) * 2 + kb;
      const char* gb = (const char*)B + ((size_t)(n0 + row) * K + k0) * 2 + kb;
      __builtin_amdgcn_global_load_lds((const GAS void*)ga,
                                       (LAS void*)((char*)As + c * 1024), 16, 0, 0);
      __builtin_amdgcn_global_load_lds((const GAS void*)gb,
                                       (LAS void*)((char*)Bs + c * 1024), 16, 0, 0);
    }
    asm volatile("s_waitcnt vmcnt(0)" ::: "memory");
    __syncthreads();
    bf16x8 af[4], bfr[4];
#pragma unroll
    for (int i = 0; i < 4; ++i)
      af[i] = *(const bf16x8*)&As[(wr * 64 + i * 16 + lr) * 32 + lk * 8];
#pragma unroll
    for (int i = 0; i < 4; ++i)
      bfr[i] = *(const bf16x8*)&Bs[(wc * 64 + i * 16 + lr) * 32 + lk * 8];
#pragma unroll
    for (int i = 0; i < 4; ++i)
#pragma unroll
      for (int jj = 0; jj < 4; ++jj)
        acc[i][jj] = __builtin_amdgcn_mfma_f32_16x16x32_bf16(af[i], bfr[jj], acc[i][jj], 0, 0, 0);
    __syncthreads();
  }
#pragma unroll
  for (int jj = 0; jj < 4; ++jj) {
    int col = n0 + wc * 64 + jj * 16 + lr;
    float bv = bias ? bias[col] : 0.f;
#pragma unroll
    for (int i = 0; i < 4; ++i) {
      int rb = m0 + wr * 64 + i * 16 + lk * 4;
#pragma unroll
      for (int q = 0; q < 4; ++q)
        C[(size_t)(rb + q) * N + col] = acc[i][jj][q] + bv;
    }
  }
}

// ---------------- mega kernel: rnn (wg 0..31) + decode (wg 32..255) ----------
// rnn: round-4 protocol verbatim (MALL flags + MALL exchange), outsb now
// agent-stored so decode wgs can consume it mid-kernel.
// decode: per step t, poll all 128 (g,band) flags >= 3t+2, then GEMM
// outsb[t] [64,512] x decbf^T for this wg's n-tiles. One-way dep -> no deadlock.
struct MegaP {
  const float *Whh, *ztW, *rtW, *htW;
  const float *gi, *ztp, *rtp, *wemb, *inith, *bhh, *htb;
  _Float16 *hcurF, *hgruF, *rwF;
  unsigned short *outsb;
  float *hfin;
  unsigned *flags;            // 128 slots (g*4+w), 64B apart
  const unsigned short *decbf;
  const float *decb;
  float *outC;
};

__device__ __forceinline__ void poll_band(const unsigned* flags, int w, int l,
                                          unsigned tgt) {
  const unsigned* fp = flags + ((size_t)((l & 31) * 4 + w)) * 16;
  for (;;) {
    unsigned v = ldf_mall(fp);
    if (__all((int)(v >= tgt))) break;
  }
}

template <int NT>
__device__ __forceinline__ void mm_mall(f32x4* acc, const _Float16* A,
                                        const _Float16* WLrow, int w, int lr, int lk) {
  f16x8 af[16];
  const _Float16* arow = A + ((size_t)(16 * w + lr)) * 512 + lk * 8;
#define LDA(c) af[c] = ldh8_mall<(c) * 64>(arow);
  LDA(0) LDA(1) LDA(2) LDA(3) LDA(4) LDA(5) LDA(6) LDA(7)
  LDA(8) LDA(9) LDA(10) LDA(11) LDA(12) LDA(13) LDA(14) LDA(15)
#undef LDA
  asm volatile("s_waitcnt vmcnt(0)" ::: "memory");
  __builtin_amdgcn_sched_barrier(0);
#pragma unroll
  for (int c = 0; c < 16; ++c) {
#pragma unroll
    for (int n = 0; n < NT; ++n) {
      f16x8 bb = *(const f16x8*)(WLrow + (n * 16 + lr) * 520 + c * 32 + lk * 8);
      acc[n] = __builtin_amdgcn_mfma_f32_16x16x32_f16(af[c], bb, acc[n], 0, 0, 0);
    }
  }
}

__global__ __launch_bounds__(256) void k_mega(MegaP p) {
  __shared__ __align__(16) char LSD[116480];
  const int tid = threadIdx.x;
  const int w = tid >> 6, l = tid & 63;
  const int lr = l & 15, lk = l >> 4;

  if (blockIdx.x < 32) {
    // ================= RNN role (round-4 verbatim) =================
    const int g = blockIdx.x;
    _Float16* WL = (_Float16*)LSD;  // 112 x 520
    for (int idx = tid; idx < 112 * 512; idx += 256) {
      int rr = idx >> 9, e = idx & 511;
      const float* src;
      if (rr < 48) {
        int gate = rr >> 4, i = rr & 15;
        src = p.Whh + ((size_t)(gate * 512 + g * 16 + i)) * 512 + e;
      } else if (rr < 96) {
        int r2 = rr - 48, gate = r2 >> 4, i = r2 & 15;
        const float* base = gate == 0 ? p.ztW : (gate == 1 ? p.rtW : p.htW);
        src = base + ((size_t)(g * 16 + i)) * 1024 + 512 + e;
      } else {
        int i = rr - 96;
        src = p.htW + ((size_t)(g * 16 + i)) * 1024 + e;
      }
      WL[rr * 520 + e] = (_Float16)(*src);
    }
    const int j = g * 16 + lr;
    const int brow = 16 * w + lk * 4;
    f32x4 hprev, zp, rp, wev;
#pragma unroll
    for (int q = 0; q < 4; ++q) {
      int b = brow + q;
      hprev[q] = p.inith[(size_t)b * 512 + j];
      zp[q] = p.ztp[(size_t)b * 512 + j];
      rp[q] = p.rtp[(size_t)b * 512 + j];
      wev[q] = p.wemb[(size_t)b * 512 + j];
      st2c(&p.hcurF[(size_t)b * 512 + j], (_Float16)hprev[q]);
    }
    const float br = p.bhh[j], bz = p.bhh[512 + j], bn = p.bhh[1024 + j];
    const float bht = p.htb[j];
    float gir[12];
#pragma unroll
    for (int q = 0; q < 4; ++q) {
      const float* git = p.gi + (size_t)(brow + q) * 1536;
      gir[q * 3 + 0] = git[j];
      gir[q * 3 + 1] = git[512 + j];
      gir[q * 3 + 2] = git[1024 + j];
    }
    __syncthreads();  // WL ready
    asm volatile("s_waitcnt vmcnt(0)" ::: "memory");
    if (tid == 0) stf_mall(p.flags + (size_t)(g * 4 + 0) * 16, 1u);
    else if (tid == 64) stf_mall(p.flags + (size_t)(g * 4 + 1) * 16, 1u);
    else if (tid == 128) stf_mall(p.flags + (size_t)(g * 4 + 2) * 16, 1u);
    else if (tid == 192) stf_mall(p.flags + (size_t)(g * 4 + 3) * 16, 1u);

    for (int t = 0; t < 64; ++t) {
      const unsigned base = 3u * (unsigned)t;
      // ---- phase 1 ----
      poll_band(p.flags, w, l, base + 1);
      f32x4 acc1[3] = {};
      mm_mall<3>(acc1, p.hcurF, &WL[0], w, lr, lk);
      f32x4 hg;
#pragma unroll
      for (int q = 0; q < 4; ++q) {
        int b = brow + q;
        float r = sigmoidf(gir[q * 3 + 0] + br + acc1[0][q]);
        float z = sigmoidf(gir[q * 3 + 1] + bz + acc1[1][q]);
        float n = tanhf(gir[q * 3 + 2] + r * (acc1[2][q] + bn));
        float hgq = (1.f - z) * n + z * hprev[q];
        hg[q] = hgq;
        st2c(&p.hgruF[(size_t)b * 512 + j], (_Float16)hgq);
        stu2c(&p.outsb[((size_t)t * 64 + b) * 512 + j], f2bf(hgq));
      }
      asm volatile("s_waitcnt vmcnt(0)" ::: "memory");
      if (l == 0) stf_mall(p.flags + ((size_t)(g * 4 + w)) * 16, base + 2);
      // ---- phase 2 ----
      poll_band(p.flags, w, l, base + 2);
      f32x4 acc2[3] = {};
      mm_mall<3>(acc2, p.hgruF, &WL[48 * 520], w, lr, lk);
      f32x4 zt, htB;
#pragma unroll
      for (int q = 0; q < 4; ++q) {
        int b = brow + q;
        float ztq = sigmoidf(zp[q] + acc2[0][q]);
        float rtq = sigmoidf(rp[q] + acc2[1][q]);
        zt[q] = ztq;
        htB[q] = acc2[2][q];
        st2c(&p.rwF[(size_t)b * 512 + j], (_Float16)(rtq * wev[q]));
      }
      asm volatile("s_waitcnt vmcnt(0)" ::: "memory");
      if (l == 0) stf_mall(p.flags + ((size_t)(g * 4 + w)) * 16, base + 3);
      // gi prefetch for t+1
      if (t < 63) {
        const float* git = p.gi + (size_t)(t + 1) * 64 * 1536;
#pragma unroll
        for (int q = 0; q < 4; ++q) {
          const float* gb = git + (size_t)(brow + q) * 1536;
          gir[q * 3 + 0] = gb[j];
          gir[q * 3 + 1] = gb[512 + j];
          gir[q * 3 + 2] = gb[1024 + j];
        }
      }
      // ---- phase 3 ----
      poll_band(p.flags, w, l, base + 3);
      f32x4 acc3[1] = {};
      mm_mall<1>(acc3, p.rwF, &WL[96 * 520], w, lr, lk);
#pragma unroll
      for (int q = 0; q < 4; ++q) {
        int b = brow + q;
        float htl = tanhf(acc3[0][q] + htB[q] + bht);
        float hn2 = (1.f - zt[q]) * hg[q] + zt[q] * htl;
        hprev[q] = hn2;
        if (t < 63) st2c(&p.hcurF[(size_t)b * 512 + j], (_Float16)hn2);
        else p.hfin[(size_t)b * 512 + j] = hn2;
      }
      if (t < 63) {
        asm volatile("s_waitcnt vmcnt(0)" ::: "memory");
        if (l == 0) stf_mall(p.flags + ((size_t)(g * 4 + w)) * 16, base + 4);
      }
    }
  } else {
    // ================= DECODE role =================
    const int d = blockIdx.x - 32;  // 0..223
    unsigned short* As = (unsigned short*)LSD;                  // [64][520] bf16
    unsigned short* Bs = (unsigned short*)(LSD + 64 * 520 * 2); // [128][32] bf16
    for (int t = 0; t < 64; ++t) {
      const unsigned tgt = 3u * (unsigned)t + 2u;
      // poll all 128 (g,band) flags
      {
        const unsigned* f0 = p.flags + (size_t)l * 16;
        const unsigned* f1 = p.flags + (size_t)(l + 64) * 16;
        for (;;) {
          unsigned a = ldf_mall(f0);
          unsigned b = ldf_mall(f1);
          if (__all((int)(a >= tgt && b >= tgt))) break;
        }
      }
      __syncthreads();  // As free to overwrite (prev step's frags consumed)
      // stage A = outsb[t] [64,512] via MALL loads -> LDS
      {
        u32x4 av[8];
#pragma unroll
        for (int it = 0; it < 8; ++it) {
          int fi = (tid + 256 * it) * 8;
          av[it] = ld16_mall(p.outsb + ((size_t)t * 64 + (fi >> 9)) * 512 + (fi & 511));
        }
        asm volatile("s_waitcnt vmcnt(0)" ::: "memory");
#pragma unroll
        for (int it = 0; it < 8; ++it) {
          int fi = (tid + 256 * it) * 8;
          *(u32x4*)&As[(fi >> 9) * 520 + (fi & 511)] = av[it];
        }
#pragma unroll
        for (int it = 8; it < 16; ++it) {
          int fi = (tid + 256 * it) * 8;
          av[it - 8] = ld16_mall(p.outsb + ((size_t)t * 64 + (fi >> 9)) * 512 + (fi & 511));
        }
        asm volatile("s_waitcnt vmcnt(0)" ::: "memory");
#pragma unroll
        for (int it = 8; it < 16; ++it) {
          int fi = (tid + 256 * it) * 8;
          *(u32x4*)&As[(fi >> 9) * 520 + (fi & 511)] = av[it - 8];
        }
      }
      __syncthreads();
      // this wg's n-tiles: d and d+224 (250 total)
#pragma unroll 1
      for (int tix = 0; tix < 2; ++tix) {
        int tile = d + tix * 224;
        if (tile >= 250) break;
        int n0 = tile * 128;
        f32x4 acc[8] = {};
        for (int k0 = 0; k0 < 512; k0 += 32) {
#pragma unroll
          for (int i = 0; i < 2; ++i) {
            int c = w * 2 + i;
            int off = c * 1024 + l * 16;
            int row = off >> 6, kb = off & 63;
            const char* gb = (const char*)p.decbf + ((size_t)(n0 + row) * 512 + k0) * 2 + kb;
            __builtin_amdgcn_global_load_lds((const GAS void*)gb,
                                             (LAS void*)((char*)Bs + c * 1024), 16, 0, 0);
          }
          asm volatile("s_waitcnt vmcnt(0)" ::: "memory");
          __syncthreads();
          bf16x8 af = *(const bf16x8*)&As[(16 * w + lr) * 520 + k0 + lk * 8];
#pragma unroll
          for (int n = 0; n < 8; ++n) {
            bf16x8 bfr = *(const bf16x8*)&Bs[(n * 16 + lr) * 32 + lk * 8];
            acc[n] = __builtin_amdgcn_mfma_f32_16x16x32_bf16(af, bfr, acc[n], 0, 0, 0);
          }
          __syncthreads();
        }
#pragma unroll
        for (int n = 0; n < 8; ++n) {
          int col = n0 + n * 16 + lr;
          float bv = p.decb[col];
#pragma unroll
          for (int q = 0; q < 4; ++q) {
            int row = t * 64 + 16 * w + lk * 4 + q;
            p.outC[(size_t)row * 32000 + col] = acc[n][q] + bv;
          }
        }
      }
    }
  }
}

extern "C" void kernel_launch(void* const* d_in, const int* in_sizes, int n_in,
                              void* d_out, int out_size, void* d_ws, size_t ws_size,
                              hipStream_t stream) {
  const float* emb   = (const float*)d_in[0];
  const float* Wih   = (const float*)d_in[1];
  const float* Whh   = (const float*)d_in[2];
  const float* bih   = (const float*)d_in[3];
  const float* bhh   = (const float*)d_in[4];
  const float* ztW   = (const float*)d_in[5];
  const float* ztb   = (const float*)d_in[6];
  const float* rtW   = (const float*)d_in[7];
  const float* rtb   = (const float*)d_in[8];
  const float* htW   = (const float*)d_in[9];
  const float* htb   = (const float*)d_in[10];
  const float* decW  = (const float*)d_in[11];
  const float* decb  = (const float*)d_in[12];
  const float* inith = (const float*)d_in[13];
  const int* word    = (const int*)d_in[14];
  const int* seq     = (const int*)d_in[15];
  float* out = (float*)d_out;

  char* ws = (char*)d_ws;
  size_t off = 0;
  auto alloc = [&](size_t bytes) {
    size_t o = off;
    off += (bytes + 255) & ~(size_t)255;
    return o;
  };
  unsigned short* xbf   = (unsigned short*)(ws + alloc(4096ull * 512 * 2));
  unsigned short* wihbf = (unsigned short*)(ws + alloc(1536ull * 512 * 2));
  unsigned short* decbf = (unsigned short*)(ws + alloc(32000ull * 512 * 2));
  float* wemb           = (float*)(ws + alloc(64ull * 512 * 4));
  float* ztp            = (float*)(ws + alloc(64ull * 512 * 4));
  float* rtp            = (float*)(ws + alloc(64ull * 512 * 4));
  float* gi             = (float*)(ws + alloc(4096ull * 1536 * 4));
  unsigned short* outsb = (unsigned short*)(ws + alloc(4096ull * 512 * 2));
  _Float16* hcurF       = (_Float16*)(ws + alloc(64ull * 512 * 2));
  _Float16* hgruF       = (_Float16*)(ws + alloc(64ull * 512 * 2));
  _Float16* rwF         = (_Float16*)(ws + alloc(64ull * 512 * 2));
  unsigned* flags       = (unsigned*)(ws + alloc(128 * 64));

  hipLaunchKernelGGL(k_gather, dim3(4160), dim3(128), 0, stream,
                     emb, seq, word, xbf, wemb);
  hipLaunchKernelGGL(k_conv, dim3(33536), dim3(128), 0, stream,
                     Wih, decW, wihbf, decbf);
  hipLaunchKernelGGL(k_pre, dim3(256), dim3(256), 0, stream,
                     ztW, ztb, rtW, rtb, wemb, ztp, rtp);
  hipLaunchKernelGGL(k_gemm_bt, dim3(384), dim3(256), 0, stream,
                     xbf, wihbf, gi, bih, 4096, 1536, 512);
  hipMemsetAsync(flags, 0, 128 * 64, stream);
  MegaP p{Whh, ztW, rtW, htW, gi, ztp, rtp, wemb, inith, bhh, htb,
          hcurF, hgruF, rwF, outsb, out + 4096ull * 32000, flags,
          decbf, decb, out};
  hipLaunchKernelGGL(k_mega, dim3(256), dim3(256), 0, stream, p);
}

// Round 8
// 1420.797 us; speedup vs baseline: 1.3578x; 1.0056x over previous
//
#include <hip/hip_runtime.h>
#include <stdint.h>

#define GAS __attribute__((address_space(1)))
#define LAS __attribute__((address_space(3)))

typedef __bf16 bf16x8 __attribute__((ext_vector_type(8)));
typedef _Float16 f16x8 __attribute__((ext_vector_type(8)));
typedef float f32x4 __attribute__((ext_vector_type(4)));
typedef unsigned u32x4 __attribute__((ext_vector_type(4)));

__device__ __forceinline__ unsigned short f2bf(float f) {
  unsigned u = __float_as_uint(f);
  unsigned r = (u + 0x7FFFu + ((u >> 16) & 1u)) >> 16;
  return (unsigned short)r;
}

__device__ __forceinline__ float sigmoidf(float x) {
  return 1.f / (1.f + expf(-x));
}

// ---- MALL-coherent (agent) exchange primitives (verified r3/r4) --------------
__device__ __forceinline__ void st2c(_Float16* p, _Float16 v) {
  unsigned short u = __builtin_bit_cast(unsigned short, v);
  __hip_atomic_store((unsigned short*)p, u, __ATOMIC_RELAXED, __HIP_MEMORY_SCOPE_AGENT);
}
__device__ __forceinline__ void stf_mall(unsigned* p, unsigned v) {
  __hip_atomic_store(p, v, __ATOMIC_RELAXED, __HIP_MEMORY_SCOPE_AGENT);
}
__device__ __forceinline__ unsigned ldf_mall(const unsigned* p) {
  return __hip_atomic_load(p, __ATOMIC_RELAXED, __HIP_MEMORY_SCOPE_AGENT);
}
// 16B MALL-coherent load; result IN FLIGHT until s_waitcnt vmcnt(0)!
template <int OFF>
__device__ __forceinline__ f16x8 ldh8_mall(const _Float16* p) {
  u32x4 r;
  asm volatile("global_load_dwordx4 %0, %1, off offset:%2 sc0 sc1"
               : "=v"(r) : "v"(p), "n"(OFF) : "memory");
  return __builtin_bit_cast(f16x8, r);
}

// ---------------- gather: x_bf16 [4096,512] from seq; word_emb f32 [64,512] ----
__global__ __launch_bounds__(128) void k_gather(
    const float* __restrict__ emb, const int* __restrict__ seq,
    const int* __restrict__ word, unsigned short* __restrict__ xbf,
    float* __restrict__ wemb) {
  int row = blockIdx.x;
  int tid = threadIdx.x;
  if (row < 4096) {
    const float* src = emb + (size_t)seq[row] * 512;
    unsigned short* dst = xbf + (size_t)row * 512;
    for (int e = tid; e < 512; e += 128) dst[e] = f2bf(src[e]);
  } else {
    int b = row - 4096;
    const float* src = emb + (size_t)word[b] * 512;
    float* dst = wemb + (size_t)b * 512;
    for (int e = tid; e < 512; e += 128) dst[e] = src[e];
  }
}

// ---------------- weight conversion: wih_bf [1536,512], dec_bf [32000,512] ----
__global__ __launch_bounds__(128) void k_conv(
    const float* __restrict__ Wih, const float* __restrict__ decW,
    unsigned short* __restrict__ wih_bf, unsigned short* __restrict__ dec_bf) {
  int row = blockIdx.x;
  int tid = threadIdx.x;
  if (row < 1536) {
    const float* s = Wih + (size_t)row * 512;
    unsigned short* d = wih_bf + (size_t)row * 512;
    for (int e = tid; e < 512; e += 128) d[e] = f2bf(s[e]);
  } else {
    int o = row - 1536;
    const float* s = decW + (size_t)o * 512;
    unsigned short* d = dec_bf + (size_t)o * 512;
    for (int e = tid; e < 512; e += 128) d[e] = f2bf(s[e]);
  }
}

// ---------------- step-invariant gate preactivations from word_emb ------------
__global__ __launch_bounds__(256) void k_pre(
    const float* __restrict__ ztW, const float* __restrict__ ztb,
    const float* __restrict__ rtW, const float* __restrict__ rtb,
    const float* __restrict__ wemb, float* __restrict__ ztp,
    float* __restrict__ rtp) {
  int idx = blockIdx.x * 256 + threadIdx.x;
  int b = idx >> 10, o = idx & 1023;
  const float4* we = (const float4*)(wemb + (size_t)b * 512);
  const float4* wr;
  float acc;
  if (o < 512) { wr = (const float4*)(ztW + (size_t)o * 1024); acc = ztb[o]; }
  else { wr = (const float4*)(rtW + (size_t)(o - 512) * 1024); acc = rtb[o - 512]; }
  for (int c = 0; c < 128; ++c) {
    float4 w = wr[c], e = we[c];
    acc += w.x * e.x + w.y * e.y + w.z * e.z + w.w * e.w;
  }
  if (o < 512) ztp[(size_t)b * 512 + o] = acc;
  else rtp[(size_t)b * 512 + (o - 512)] = acc;
}

// ---------------- bf16 GEMM, C[m,n] = sum_k A[m,k]*B[n,k] + bias[n] ----------
__global__ __launch_bounds__(256) void k_gemm_bt(
    const unsigned short* __restrict__ A, const unsigned short* __restrict__ B,
    float* __restrict__ C, const float* __restrict__ bias,
    int M, int N, int K) {
  __shared__ __align__(16) unsigned short As[128 * 32];
  __shared__ __align__(16) unsigned short Bs[128 * 32];
  int nt = N >> 7;
  int nwg = gridDim.x;
  int bid = blockIdx.x;
  int swz = (bid & 7) * (nwg >> 3) + (bid >> 3);  // XCD swizzle (nwg % 8 == 0)
  int m0 = (swz / nt) << 7, n0 = (swz % nt) << 7;
  int tid = threadIdx.x;
  int l = tid & 63, w = tid >> 6;
  int wr = w >> 1, wc = w & 1;
  int lr = l & 15, lk = l >> 4;
  f32x4 acc[4][4] = {};
  for (int k0 = 0; k0 < K; k0 += 32) {
#pragma unroll
    for (int i = 0; i < 2; ++i) {
      int c = w * 2 + i;
      int off = c * 1024 + l * 16;
      int row = off >> 6, kb = off & 63;
      const char* ga = (const char*)A + ((size_t)(m0 + row) * K + k0) * 2 + kb;
      const char* gb = (const char*)B + ((size_t)(n0 + row) * K + k0) * 2 + kb;
      __builtin_amdgcn_global_load_lds((const GAS void*)ga,
                                       (LAS void*)((char*)As + c * 1024), 16, 0, 0);
      __builtin_amdgcn_global_load_lds((const GAS void*)gb,
                                       (LAS void*)((char*)Bs + c * 1024), 16, 0, 0);
    }
    asm volatile("s_waitcnt vmcnt(0)" ::: "memory");
    __syncthreads();
    bf16x8 af[4], bfr[4];
#pragma unroll
    for (int i = 0; i < 4; ++i)
      af[i] = *(const bf16x8*)&As[(wr * 64 + i * 16 + lr) * 32 + lk * 8];
#pragma unroll
    for (int i = 0; i < 4; ++i)
      bfr[i] = *(const bf16x8*)&Bs[(wc * 64 + i * 16 + lr) * 32 + lk * 8];
#pragma unroll
    for (int i = 0; i < 4; ++i)
#pragma unroll
      for (int jj = 0; jj < 4; ++jj)
        acc[i][jj] = __builtin_amdgcn_mfma_f32_16x16x32_bf16(af[i], bfr[jj], acc[i][jj], 0, 0, 0);
    __syncthreads();
  }
#pragma unroll
  for (int jj = 0; jj < 4; ++jj) {
    int col = n0 + wc * 64 + jj * 16 + lr;
    float bv = bias ? bias[col] : 0.f;
#pragma unroll
    for (int i = 0; i < 4; ++i) {
      int rb = m0 + wr * 64 + i * 16 + lk * 4;
#pragma unroll
      for (int q = 0; q < 4; ++q)
        C[(size_t)(rb + q) * N + col] = acc[i][jj][q] + bv;
    }
  }
}

// ---------------- recurrence: 32 wgs, column ownership, LDS weights -----------
// r4 protocol with hop optimizations:
//  * packed flags: u32 flags[w*32+g] — band poll = one coalesced 128B fetch
//  * drain-before-flag covers ONLY the 4 exchange stores (outsb/gi moved after)
//  * gi prefetch issued at phase-1 tail (2 phases of slack)
struct RnnP {
  const float *Whh, *ztW, *rtW, *htW;
  const float *gi, *ztp, *rtp, *wemb, *inith, *bhh, *htb;
  _Float16 *hcurF, *hgruF, *rwF;
  unsigned short *outsb;
  float *hfin;
  unsigned *flags;  // [4 bands][32 wgs], 4B stride, 128B per band
};

__device__ __forceinline__ void poll_band(const unsigned* flags, int w, int l,
                                          unsigned tgt) {
  const unsigned* fp = flags + w * 32 + (l & 31);
  for (;;) {
    unsigned v = ldf_mall(fp);
    if (__all((int)(v >= tgt))) break;
  }
}

// acc[n] += A[64,512] (band rows 16w..16w+16) x WL-slice (NT tiles of 16 cols)
template <int NT>
__device__ __forceinline__ void mm_mall(f32x4* acc, const _Float16* A,
                                        const _Float16* WLrow, int w, int lr, int lk) {
  f16x8 af[16];
  const _Float16* arow = A + ((size_t)(16 * w + lr)) * 512 + lk * 8;
#define LDA(c) af[c] = ldh8_mall<(c) * 64>(arow);
  LDA(0) LDA(1) LDA(2) LDA(3) LDA(4) LDA(5) LDA(6) LDA(7)
  LDA(8) LDA(9) LDA(10) LDA(11) LDA(12) LDA(13) LDA(14) LDA(15)
#undef LDA
  asm volatile("s_waitcnt vmcnt(0)" ::: "memory");
  __builtin_amdgcn_sched_barrier(0);
#pragma unroll
  for (int c = 0; c < 16; ++c) {
#pragma unroll
    for (int n = 0; n < NT; ++n) {
      f16x8 bb = *(const f16x8*)(WLrow + (n * 16 + lr) * 520 + c * 32 + lk * 8);
      acc[n] = __builtin_amdgcn_mfma_f32_16x16x32_f16(af[c], bb, acc[n], 0, 0, 0);
    }
  }
}

__global__ __launch_bounds__(256) void k_rnn5(RnnP p) {
  const int g = blockIdx.x, tid = threadIdx.x;
  const int w = tid >> 6, l = tid & 63;
  const int lr = l & 15, lk = l >> 4;
  unsigned* myflag = p.flags + w * 32 + g;
  // 112 rows x 520 halfs (512 + 8 pad)
  __shared__ _Float16 WL[112 * 520];
  for (int idx = tid; idx < 112 * 512; idx += 256) {
    int rr = idx >> 9, e = idx & 511;
    const float* src;
    if (rr < 48) {
      int gate = rr >> 4, i = rr & 15;
      src = p.Whh + ((size_t)(gate * 512 + g * 16 + i)) * 512 + e;
    } else if (rr < 96) {
      int r2 = rr - 48, gate = r2 >> 4, i = r2 & 15;
      const float* base = gate == 0 ? p.ztW : (gate == 1 ? p.rtW : p.htW);
      src = base + ((size_t)(g * 16 + i)) * 1024 + 512 + e;
    } else {
      int i = rr - 96;
      src = p.htW + ((size_t)(g * 16 + i)) * 1024 + e;
    }
    WL[rr * 520 + e] = (_Float16)(*src);
  }
  // ---- per-lane owned coordinates: col j, batch rows brow..brow+3 ----
  const int j = g * 16 + lr;
  const int brow = 16 * w + lk * 4;
  f32x4 hprev, zp, rp, wev;
#pragma unroll
  for (int q = 0; q < 4; ++q) {
    int b = brow + q;
    hprev[q] = p.inith[(size_t)b * 512 + j];
    zp[q] = p.ztp[(size_t)b * 512 + j];
    rp[q] = p.rtp[(size_t)b * 512 + j];
    wev[q] = p.wemb[(size_t)b * 512 + j];
    st2c(&p.hcurF[(size_t)b * 512 + j], (_Float16)hprev[q]);
  }
  const float br = p.bhh[j], bz = p.bhh[512 + j], bn = p.bhh[1024 + j];
  const float bht = p.htb[j];
  float gir[12];
#pragma unroll
  for (int q = 0; q < 4; ++q) {
    const float* git = p.gi + (size_t)(brow + q) * 1536;
    gir[q * 3 + 0] = git[j];
    gir[q * 3 + 1] = git[512 + j];
    gir[q * 3 + 2] = git[1024 + j];
  }
  __syncthreads();  // WL ready; also drains all stores/loads above
  if (l == 0) stf_mall(myflag, 1u);

  for (int t = 0; t < 64; ++t) {
    const unsigned base = 3u * (unsigned)t;
    // ---- phase 1: gates r,z,n ; h_gru ----
    poll_band(p.flags, w, l, base + 1);
    f32x4 acc1[3] = {};
    mm_mall<3>(acc1, p.hcurF, &WL[0], w, lr, lk);
    f32x4 hg;
#pragma unroll
    for (int q = 0; q < 4; ++q) {
      int b = brow + q;
      float r = sigmoidf(gir[q * 3 + 0] + br + acc1[0][q]);
      float z = sigmoidf(gir[q * 3 + 1] + bz + acc1[1][q]);
      float n = tanhf(gir[q * 3 + 2] + r * (acc1[2][q] + bn));
      float hgq = (1.f - z) * n + z * hprev[q];
      hg[q] = hgq;
      st2c(&p.hgruF[(size_t)b * 512 + j], (_Float16)hgq);
    }
    asm volatile("s_waitcnt vmcnt(0)" ::: "memory");
    if (l == 0) stf_mall(myflag, base + 2);
    // deferred: outsb stores + next-step gi prefetch (off the critical path)
#pragma unroll
    for (int q = 0; q < 4; ++q)
      p.outsb[((size_t)t * 64 + brow + q) * 512 + j] = f2bf(hg[q]);
    if (t < 63) {
      const float* git = p.gi + (size_t)(t + 1) * 64 * 1536;
#pragma unroll
      for (int q = 0; q < 4; ++q) {
        const float* gb = git + (size_t)(brow + q) * 1536;
        gir[q * 3 + 0] = gb[j];
        gir[q * 3 + 1] = gb[512 + j];
        gir[q * 3 + 2] = gb[1024 + j];
      }
    }
    // ---- phase 2: zt, rt, htB ----
    poll_band(p.flags, w, l, base + 2);
    f32x4 acc2[3] = {};
    mm_mall<3>(acc2, p.hgruF, &WL[48 * 520], w, lr, lk);
    f32x4 zt, htB;
#pragma unroll
    for (int q = 0; q < 4; ++q) {
      int b = brow + q;
      float ztq = sigmoidf(zp[q] + acc2[0][q]);
      float rtq = sigmoidf(rp[q] + acc2[1][q]);
      zt[q] = ztq;
      htB[q] = acc2[2][q];
      st2c(&p.rwF[(size_t)b * 512 + j], (_Float16)(rtq * wev[q]));
    }
    asm volatile("s_waitcnt vmcnt(0)" ::: "memory");
    if (l == 0) stf_mall(myflag, base + 3);
    // ---- phase 3: htA ; h_new ----
    poll_band(p.flags, w, l, base + 3);
    f32x4 acc3[1] = {};
    mm_mall<1>(acc3, p.rwF, &WL[96 * 520], w, lr, lk);
#pragma unroll
    for (int q = 0; q < 4; ++q) {
      int b = brow + q;
      float htl = tanhf(acc3[0][q] + htB[q] + bht);
      float hn2 = (1.f - zt[q]) * hg[q] + zt[q] * htl;
      hprev[q] = hn2;
      if (t < 63) st2c(&p.hcurF[(size_t)b * 512 + j], (_Float16)hn2);
      else p.hfin[(size_t)b * 512 + j] = hn2;
    }
    if (t < 63) {
      asm volatile("s_waitcnt vmcnt(0)" ::: "memory");
      if (l == 0) stf_mall(myflag, base + 4);
    }
  }
}

extern "C" void kernel_launch(void* const* d_in, const int* in_sizes, int n_in,
                              void* d_out, int out_size, void* d_ws, size_t ws_size,
                              hipStream_t stream) {
  const float* emb   = (const float*)d_in[0];
  const float* Wih   = (const float*)d_in[1];
  const float* Whh   = (const float*)d_in[2];
  const float* bih   = (const float*)d_in[3];
  const float* bhh   = (const float*)d_in[4];
  const float* ztW   = (const float*)d_in[5];
  const float* ztb   = (const float*)d_in[6];
  const float* rtW   = (const float*)d_in[7];
  const float* rtb   = (const float*)d_in[8];
  const float* htW   = (const float*)d_in[9];
  const float* htb   = (const float*)d_in[10];
  const float* decW  = (const float*)d_in[11];
  const float* decb  = (const float*)d_in[12];
  const float* inith = (const float*)d_in[13];
  const int* word    = (const int*)d_in[14];
  const int* seq     = (const int*)d_in[15];
  float* out = (float*)d_out;

  char* ws = (char*)d_ws;
  size_t off = 0;
  auto alloc = [&](size_t bytes) {
    size_t o = off;
    off += (bytes + 255) & ~(size_t)255;
    return o;
  };
  unsigned short* xbf   = (unsigned short*)(ws + alloc(4096ull * 512 * 2));
  unsigned short* wihbf = (unsigned short*)(ws + alloc(1536ull * 512 * 2));
  unsigned short* decbf = (unsigned short*)(ws + alloc(32000ull * 512 * 2));
  float* wemb           = (float*)(ws + alloc(64ull * 512 * 4));
  float* ztp            = (float*)(ws + alloc(64ull * 512 * 4));
  float* rtp            = (float*)(ws + alloc(64ull * 512 * 4));
  float* gi             = (float*)(ws + alloc(4096ull * 1536 * 4));
  unsigned short* outsb = (unsigned short*)(ws + alloc(4096ull * 512 * 2));
  _Float16* hcurF       = (_Float16*)(ws + alloc(64ull * 512 * 2));
  _Float16* hgruF       = (_Float16*)(ws + alloc(64ull * 512 * 2));
  _Float16* rwF         = (_Float16*)(ws + alloc(64ull * 512 * 2));
  unsigned* flags       = (unsigned*)(ws + alloc(512));

  hipLaunchKernelGGL(k_gather, dim3(4160), dim3(128), 0, stream,
                     emb, seq, word, xbf, wemb);
  hipLaunchKernelGGL(k_conv, dim3(33536), dim3(128), 0, stream,
                     Wih, decW, wihbf, decbf);
  hipLaunchKernelGGL(k_pre, dim3(256), dim3(256), 0, stream,
                     ztW, ztb, rtW, rtb, wemb, ztp, rtp);
  hipLaunchKernelGGL(k_gemm_bt, dim3(384), dim3(256), 0, stream,
                     xbf, wihbf, gi, bih, 4096, 1536, 512);
  hipMemsetAsync(flags, 0, 512, stream);
  RnnP p{Whh, ztW, rtW, htW, gi, ztp, rtp, wemb, inith, bhh, htb,
         hcurF, hgruF, rwF, outsb, out + 4096ull * 32000, flags};
  hipLaunchKernelGGL(k_rnn5, dim3(32), dim3(256), 0, stream, p);
  hipLaunchKernelGGL(k_gemm_bt, dim3(8000), dim3(256), 0, stream,
                     outsb, decbf, out, decb, 4096, 32000, 512);
}

// Round 9
// 1270.392 us; speedup vs baseline: 1.5185x; 1.1184x over previous
//
#include <hip/hip_runtime.h>
#include <stdint.h>

#define GAS __attribute__((address_space(1)))
#define LAS __attribute__((address_space(3)))

typedef __bf16 bf16x8 __attribute__((ext_vector_type(8)));
typedef _Float16 f16x8 __attribute__((ext_vector_type(8)));
typedef float f32x4 __attribute__((ext_vector_type(4)));
typedef unsigned u32x4 __attribute__((ext_vector_type(4)));

__device__ __forceinline__ unsigned short f2bf(float f) {
  unsigned u = __float_as_uint(f);
  unsigned r = (u + 0x7FFFu + ((u >> 16) & 1u)) >> 16;
  return (unsigned short)r;
}

__device__ __forceinline__ float sigmoidf(float x) {
  return 1.f / (1.f + expf(-x));
}

// ---- MALL-coherent (agent) exchange primitives (verified r3/r4) --------------
__device__ __forceinline__ void st2c(_Float16* p, _Float16 v) {
  unsigned short u = __builtin_bit_cast(unsigned short, v);
  __hip_atomic_store((unsigned short*)p, u, __ATOMIC_RELAXED, __HIP_MEMORY_SCOPE_AGENT);
}
__device__ __forceinline__ void stf_mall(unsigned* p, unsigned v) {
  __hip_atomic_store(p, v, __ATOMIC_RELAXED, __HIP_MEMORY_SCOPE_AGENT);
}
__device__ __forceinline__ unsigned ldf_mall(const unsigned* p) {
  return __hip_atomic_load(p, __ATOMIC_RELAXED, __HIP_MEMORY_SCOPE_AGENT);
}
// 16B MALL-coherent load; result IN FLIGHT until s_waitcnt vmcnt(0)!
template <int OFF>
__device__ __forceinline__ f16x8 ldh8_mall(const _Float16* p) {
  u32x4 r;
  asm volatile("global_load_dwordx4 %0, %1, off offset:%2 sc0 sc1"
               : "=v"(r) : "v"(p), "n"(OFF) : "memory");
  return __builtin_bit_cast(f16x8, r);
}

// ---------------- gather: x_bf16 [4096,512] from seq; word_emb f32 [64,512] ----
__global__ __launch_bounds__(128) void k_gather(
    const float* __restrict__ emb, const int* __restrict__ seq,
    const int* __restrict__ word, unsigned short* __restrict__ xbf,
    float* __restrict__ wemb) {
  int row = blockIdx.x;
  int tid = threadIdx.x;
  if (row < 4096) {
    const float* src = emb + (size_t)seq[row] * 512;
    unsigned short* dst = xbf + (size_t)row * 512;
    for (int e = tid; e < 512; e += 128) dst[e] = f2bf(src[e]);
  } else {
    int b = row - 4096;
    const float* src = emb + (size_t)word[b] * 512;
    float* dst = wemb + (size_t)b * 512;
    for (int e = tid; e < 512; e += 128) dst[e] = src[e];
  }
}

// ---------------- weight conversion: wih_bf [1536,512], dec_bf [32000,512] ----
__global__ __launch_bounds__(128) void k_conv(
    const float* __restrict__ Wih, const float* __restrict__ decW,
    unsigned short* __restrict__ wih_bf, unsigned short* __restrict__ dec_bf) {
  int row = blockIdx.x;
  int tid = threadIdx.x;
  if (row < 1536) {
    const float* s = Wih + (size_t)row * 512;
    unsigned short* d = wih_bf + (size_t)row * 512;
    for (int e = tid; e < 512; e += 128) d[e] = f2bf(s[e]);
  } else {
    int o = row - 1536;
    const float* s = decW + (size_t)o * 512;
    unsigned short* d = dec_bf + (size_t)o * 512;
    for (int e = tid; e < 512; e += 128) d[e] = f2bf(s[e]);
  }
}

// ---------------- step-invariant gate preactivations from word_emb ------------
__global__ __launch_bounds__(256) void k_pre(
    const float* __restrict__ ztW, const float* __restrict__ ztb,
    const float* __restrict__ rtW, const float* __restrict__ rtb,
    const float* __restrict__ wemb, float* __restrict__ ztp,
    float* __restrict__ rtp) {
  int idx = blockIdx.x * 256 + threadIdx.x;
  int b = idx >> 10, o = idx & 1023;
  const float4* we = (const float4*)(wemb + (size_t)b * 512);
  const float4* wr;
  float acc;
  if (o < 512) { wr = (const float4*)(ztW + (size_t)o * 1024); acc = ztb[o]; }
  else { wr = (const float4*)(rtW + (size_t)(o - 512) * 1024); acc = rtb[o - 512]; }
  for (int c = 0; c < 128; ++c) {
    float4 w = wr[c], e = we[c];
    acc += w.x * e.x + w.y * e.y + w.z * e.z + w.w * e.w;
  }
  if (o < 512) ztp[(size_t)b * 512 + o] = acc;
  else rtp[(size_t)b * 512 + (o - 512)] = acc;
}

// ---------------- bf16 GEMM, C[m,n] = sum_k A[m,k]*B[n,k] + bias[n] ----------
__global__ __launch_bounds__(256) void k_gemm_bt(
    const unsigned short* __restrict__ A, const unsigned short* __restrict__ B,
    float* __restrict__ C, const float* __restrict__ bias,
    int M, int N, int K) {
  __shared__ __align__(16) unsigned short As[128 * 32];
  __shared__ __align__(16) unsigned short Bs[128 * 32];
  int nt = N >> 7;
  int nwg = gridDim.x;
  int bid = blockIdx.x;
  int swz = (bid & 7) * (nwg >> 3) + (bid >> 3);  // XCD swizzle (nwg % 8 == 0)
  int m0 = (swz / nt) << 7, n0 = (swz % nt) << 7;
  int tid = threadIdx.x;
  int l = tid & 63, w = tid >> 6;
  int wr = w >> 1, wc = w & 1;
  int lr = l & 15, lk = l >> 4;
  f32x4 acc[4][4] = {};
  for (int k0 = 0; k0 < K; k0 += 32) {
#pragma unroll
    for (int i = 0; i < 2; ++i) {
      int c = w * 2 + i;
      int off = c * 1024 + l * 16;
      int row = off >> 6, kb = off & 63;
      const char* ga = (const char*)A + ((size_t)(m0 + row) * K + k0) * 2 + kb;
      const char* gb = (const char*)B + ((size_t)(n0 + row) * K + k0) * 2 + kb;
      __builtin_amdgcn_global_load_lds((const GAS void*)ga,
                                       (LAS void*)((char*)As + c * 1024), 16, 0, 0);
      __builtin_amdgcn_global_load_lds((const GAS void*)gb,
                                       (LAS void*)((char*)Bs + c * 1024), 16, 0, 0);
    }
    asm volatile("s_waitcnt vmcnt(0)" ::: "memory");
    __syncthreads();
    bf16x8 af[4], bfr[4];
#pragma unroll
    for (int i = 0; i < 4; ++i)
      af[i] = *(const bf16x8*)&As[(wr * 64 + i * 16 + lr) * 32 + lk * 8];
#pragma unroll
    for (int i = 0; i < 4; ++i)
      bfr[i] = *(const bf16x8*)&Bs[(wc * 64 + i * 16 + lr) * 32 + lk * 8];
#pragma unroll
    for (int i = 0; i < 4; ++i)
#pragma unroll
      for (int jj = 0; jj < 4; ++jj)
        acc[i][jj] = __builtin_amdgcn_mfma_f32_16x16x32_bf16(af[i], bfr[jj], acc[i][jj], 0, 0, 0);
    __syncthreads();
  }
#pragma unroll
  for (int jj = 0; jj < 4; ++jj) {
    int col = n0 + wc * 64 + jj * 16 + lr;
    float bv = bias ? bias[col] : 0.f;
#pragma unroll
    for (int i = 0; i < 4; ++i) {
      int rb = m0 + wr * 64 + i * 16 + lk * 4;
#pragma unroll
      for (int q = 0; q < 4; ++q)
        C[(size_t)(rb + q) * N + col] = acc[i][jj][q] + bv;
    }
  }
}

// ---------------- recurrence: 32 wgs, column ownership, LDS weights -----------
// r8 structure with flags RE-SPREAD to 64B slots (single-variable diff vs r8):
//  * per-(wg,band) flags at (g*4+w)*64B — no shared-line store contention
//  * drain-before-flag covers ONLY the 4 exchange stores (outsb/gi deferred)
//  * gi prefetch issued at phase-1 tail (2 phases of slack)
struct RnnP {
  const float *Whh, *ztW, *rtW, *htW;
  const float *gi, *ztp, *rtp, *wemb, *inith, *bhh, *htb;
  _Float16 *hcurF, *hgruF, *rwF;
  unsigned short *outsb;
  float *hfin;
  unsigned *flags;  // 128 slots (g*4+w), 64B apart
};

__device__ __forceinline__ void poll_band(const unsigned* flags, int w, int l,
                                          unsigned tgt) {
  const unsigned* fp = flags + ((size_t)((l & 31) * 4 + w)) * 16;
  for (;;) {
    unsigned v = ldf_mall(fp);
    if (__all((int)(v >= tgt))) break;
  }
}

// acc[n] += A[64,512] (band rows 16w..16w+16) x WL-slice (NT tiles of 16 cols)
template <int NT>
__device__ __forceinline__ void mm_mall(f32x4* acc, const _Float16* A,
                                        const _Float16* WLrow, int w, int lr, int lk) {
  f16x8 af[16];
  const _Float16* arow = A + ((size_t)(16 * w + lr)) * 512 + lk * 8;
#define LDA(c) af[c] = ldh8_mall<(c) * 64>(arow);
  LDA(0) LDA(1) LDA(2) LDA(3) LDA(4) LDA(5) LDA(6) LDA(7)
  LDA(8) LDA(9) LDA(10) LDA(11) LDA(12) LDA(13) LDA(14) LDA(15)
#undef LDA
  asm volatile("s_waitcnt vmcnt(0)" ::: "memory");
  __builtin_amdgcn_sched_barrier(0);
#pragma unroll
  for (int c = 0; c < 16; ++c) {
#pragma unroll
    for (int n = 0; n < NT; ++n) {
      f16x8 bb = *(const f16x8*)(WLrow + (n * 16 + lr) * 520 + c * 32 + lk * 8);
      acc[n] = __builtin_amdgcn_mfma_f32_16x16x32_f16(af[c], bb, acc[n], 0, 0, 0);
    }
  }
}

__global__ __launch_bounds__(256) void k_rnn6(RnnP p) {
  const int g = blockIdx.x, tid = threadIdx.x;
  const int w = tid >> 6, l = tid & 63;
  const int lr = l & 15, lk = l >> 4;
  unsigned* myflag = p.flags + ((size_t)(g * 4 + w)) * 16;
  // 112 rows x 520 halfs (512 + 8 pad)
  __shared__ _Float16 WL[112 * 520];
  for (int idx = tid; idx < 112 * 512; idx += 256) {
    int rr = idx >> 9, e = idx & 511;
    const float* src;
    if (rr < 48) {
      int gate = rr >> 4, i = rr & 15;
      src = p.Whh + ((size_t)(gate * 512 + g * 16 + i)) * 512 + e;
    } else if (rr < 96) {
      int r2 = rr - 48, gate = r2 >> 4, i = r2 & 15;
      const float* base = gate == 0 ? p.ztW : (gate == 1 ? p.rtW : p.htW);
      src = base + ((size_t)(g * 16 + i)) * 1024 + 512 + e;
    } else {
      int i = rr - 96;
      src = p.htW + ((size_t)(g * 16 + i)) * 1024 + e;
    }
    WL[rr * 520 + e] = (_Float16)(*src);
  }
  // ---- per-lane owned coordinates: col j, batch rows brow..brow+3 ----
  const int j = g * 16 + lr;
  const int brow = 16 * w + lk * 4;
  f32x4 hprev, zp, rp, wev;
#pragma unroll
  for (int q = 0; q < 4; ++q) {
    int b = brow + q;
    hprev[q] = p.inith[(size_t)b * 512 + j];
    zp[q] = p.ztp[(size_t)b * 512 + j];
    rp[q] = p.rtp[(size_t)b * 512 + j];
    wev[q] = p.wemb[(size_t)b * 512 + j];
    st2c(&p.hcurF[(size_t)b * 512 + j], (_Float16)hprev[q]);
  }
  const float br = p.bhh[j], bz = p.bhh[512 + j], bn = p.bhh[1024 + j];
  const float bht = p.htb[j];
  float gir[12];
#pragma unroll
  for (int q = 0; q < 4; ++q) {
    const float* git = p.gi + (size_t)(brow + q) * 1536;
    gir[q * 3 + 0] = git[j];
    gir[q * 3 + 1] = git[512 + j];
    gir[q * 3 + 2] = git[1024 + j];
  }
  __syncthreads();  // WL ready; also drains all stores/loads above
  if (l == 0) stf_mall(myflag, 1u);

  for (int t = 0; t < 64; ++t) {
    const unsigned base = 3u * (unsigned)t;
    // ---- phase 1: gates r,z,n ; h_gru ----
    poll_band(p.flags, w, l, base + 1);
    f32x4 acc1[3] = {};
    mm_mall<3>(acc1, p.hcurF, &WL[0], w, lr, lk);
    f32x4 hg;
#pragma unroll
    for (int q = 0; q < 4; ++q) {
      int b = brow + q;
      float r = sigmoidf(gir[q * 3 + 0] + br + acc1[0][q]);
      float z = sigmoidf(gir[q * 3 + 1] + bz + acc1[1][q]);
      float n = tanhf(gir[q * 3 + 2] + r * (acc1[2][q] + bn));
      float hgq = (1.f - z) * n + z * hprev[q];
      hg[q] = hgq;
      st2c(&p.hgruF[(size_t)b * 512 + j], (_Float16)hgq);
    }
    asm volatile("s_waitcnt vmcnt(0)" ::: "memory");
    if (l == 0) stf_mall(myflag, base + 2);
    // deferred: outsb stores + next-step gi prefetch (off the critical path)
#pragma unroll
    for (int q = 0; q < 4; ++q)
      p.outsb[((size_t)t * 64 + brow + q) * 512 + j] = f2bf(hg[q]);
    if (t < 63) {
      const float* git = p.gi + (size_t)(t + 1) * 64 * 1536;
#pragma unroll
      for (int q = 0; q < 4; ++q) {
        const float* gb = git + (size_t)(brow + q) * 1536;
        gir[q * 3 + 0] = gb[j];
        gir[q * 3 + 1] = gb[512 + j];
        gir[q * 3 + 2] = gb[1024 + j];
      }
    }
    // ---- phase 2: zt, rt, htB ----
    poll_band(p.flags, w, l, base + 2);
    f32x4 acc2[3] = {};
    mm_mall<3>(acc2, p.hgruF, &WL[48 * 520], w, lr, lk);
    f32x4 zt, htB;
#pragma unroll
    for (int q = 0; q < 4; ++q) {
      int b = brow + q;
      float ztq = sigmoidf(zp[q] + acc2[0][q]);
      float rtq = sigmoidf(rp[q] + acc2[1][q]);
      zt[q] = ztq;
      htB[q] = acc2[2][q];
      st2c(&p.rwF[(size_t)b * 512 + j], (_Float16)(rtq * wev[q]));
    }
    asm volatile("s_waitcnt vmcnt(0)" ::: "memory");
    if (l == 0) stf_mall(myflag, base + 3);
    // ---- phase 3: htA ; h_new ----
    poll_band(p.flags, w, l, base + 3);
    f32x4 acc3[1] = {};
    mm_mall<1>(acc3, p.rwF, &WL[96 * 520], w, lr, lk);
#pragma unroll
    for (int q = 0; q < 4; ++q) {
      int b = brow + q;
      float htl = tanhf(acc3[0][q] + htB[q] + bht);
      float hn2 = (1.f - zt[q]) * hg[q] + zt[q] * htl;
      hprev[q] = hn2;
      if (t < 63) st2c(&p.hcurF[(size_t)b * 512 + j], (_Float16)hn2);
      else p.hfin[(size_t)b * 512 + j] = hn2;
    }
    if (t < 63) {
      asm volatile("s_waitcnt vmcnt(0)" ::: "memory");
      if (l == 0) stf_mall(myflag, base + 4);
    }
  }
}

extern "C" void kernel_launch(void* const* d_in, const int* in_sizes, int n_in,
                              void* d_out, int out_size, void* d_ws, size_t ws_size,
                              hipStream_t stream) {
  const float* emb   = (const float*)d_in[0];
  const float* Wih   = (const float*)d_in[1];
  const float* Whh   = (const float*)d_in[2];
  const float* bih   = (const float*)d_in[3];
  const float* bhh   = (const float*)d_in[4];
  const float* ztW   = (const float*)d_in[5];
  const float* ztb   = (const float*)d_in[6];
  const float* rtW   = (const float*)d_in[7];
  const float* rtb   = (const float*)d_in[8];
  const float* htW   = (const float*)d_in[9];
  const float* htb   = (const float*)d_in[10];
  const float* decW  = (const float*)d_in[11];
  const float* decb  = (const float*)d_in[12];
  const float* inith = (const float*)d_in[13];
  const int* word    = (const int*)d_in[14];
  const int* seq     = (const int*)d_in[15];
  float* out = (float*)d_out;

  char* ws = (char*)d_ws;
  size_t off = 0;
  auto alloc = [&](size_t bytes) {
    size_t o = off;
    off += (bytes + 255) & ~(size_t)255;
    return o;
  };
  unsigned short* xbf   = (unsigned short*)(ws + alloc(4096ull * 512 * 2));
  unsigned short* wihbf = (unsigned short*)(ws + alloc(1536ull * 512 * 2));
  unsigned short* decbf = (unsigned short*)(ws + alloc(32000ull * 512 * 2));
  float* wemb           = (float*)(ws + alloc(64ull * 512 * 4));
  float* ztp            = (float*)(ws + alloc(64ull * 512 * 4));
  float* rtp            = (float*)(ws + alloc(64ull * 512 * 4));
  float* gi             = (float*)(ws + alloc(4096ull * 1536 * 4));
  unsigned short* outsb = (unsigned short*)(ws + alloc(4096ull * 512 * 2));
  _Float16* hcurF       = (_Float16*)(ws + alloc(64ull * 512 * 2));
  _Float16* hgruF       = (_Float16*)(ws + alloc(64ull * 512 * 2));
  _Float16* rwF         = (_Float16*)(ws + alloc(64ull * 512 * 2));
  unsigned* flags       = (unsigned*)(ws + alloc(128 * 64));

  hipLaunchKernelGGL(k_gather, dim3(4160), dim3(128), 0, stream,
                     emb, seq, word, xbf, wemb);
  hipLaunchKernelGGL(k_conv, dim3(33536), dim3(128), 0, stream,
                     Wih, decW, wihbf, decbf);
  hipLaunchKernelGGL(k_pre, dim3(256), dim3(256), 0, stream,
                     ztW, ztb, rtW, rtb, wemb, ztp, rtp);
  hipLaunchKernelGGL(k_gemm_bt, dim3(384), dim3(256), 0, stream,
                     xbf, wihbf, gi, bih, 4096, 1536, 512);
  hipMemsetAsync(flags, 0, 128 * 64, stream);
  RnnP p{Whh, ztW, rtW, htW, gi, ztp, rtp, wemb, inith, bhh, htb,
         hcurF, hgruF, rwF, outsb, out + 4096ull * 32000, flags};
  hipLaunchKernelGGL(k_rnn6, dim3(32), dim3(256), 0, stream, p);
  hipLaunchKernelGGL(k_gemm_bt, dim3(8000), dim3(256), 0, stream,
                     outsb, decbf, out, decb, 4096, 32000, 512);
}